// Round 1
// baseline (923.659 us; speedup 1.0000x reference)
//
#include <hip/hip_runtime.h>

// WCT: out = S^(1/2) C^(-1/2) (xc - mu_c) + mu_s  per batch.
// B=4, C=512, H=W=128, N=16384. All big GEMMs bf16 MFMA (fp32 accum),
// matrix sqrt/invsqrt via coupled Newton-Schulz (8 iters), Gershgorin-normalized.

typedef unsigned short u16;
typedef __attribute__((ext_vector_type(8))) short bf16x8;
typedef __attribute__((ext_vector_type(4))) float f32x4;

__device__ __forceinline__ u16 f2bf(float f) {  // RNE fp32->bf16
  unsigned u = __float_as_uint(f);
  u += 0x7fffu + ((u >> 16) & 1u);
  return (u16)(u >> 16);
}

__device__ __forceinline__ void async_cp16(const u16* g, u16* l) {
  __builtin_amdgcn_global_load_lds((__attribute__((address_space(1))) void*)g,
                                   (__attribute__((address_space(3))) void*)l,
                                   16, 0, 0);
}

// NT GEMM core: C[M,N] = A[M,K] * B[N,K]^T, bf16 in LDS via global_load_lds w=16,
// 2x2 waves, 16x16x32 MFMA, BK=64. FM=BM/32, FN=BN/32.
template<int BM, int BN, int FM, int FN>
__device__ __forceinline__ void gemm_nt(const u16* __restrict__ A, int lda,
                                        const u16* __restrict__ B, int ldb,
                                        int K, f32x4 (&acc)[FM][FN],
                                        u16* lA, u16* lB) {
  const int t = threadIdx.x;
  const int lane = t & 63;
  const int wid = t >> 6;
  const int wm = wid & 1, wn = wid >> 1;
  const int l16 = lane & 15, quad = lane >> 4;
  f32x4 zero = {0.f, 0.f, 0.f, 0.f};
#pragma unroll
  for (int im = 0; im < FM; ++im)
#pragma unroll
    for (int in = 0; in < FN; ++in) acc[im][in] = zero;

  constexpr int CA = (BM * 64) / (256 * 8);  // 16B chunks per thread, A tile
  constexpr int CB = (BN * 64) / (256 * 8);

  for (int k0 = 0; k0 < K; k0 += 64) {
#pragma unroll
    for (int i = 0; i < CA; ++i) {
      int chunk = t + i * 256;  // lds offset = chunk*16B: wave-uniform base + lane*16
      async_cp16(A + (size_t)(chunk >> 3) * lda + k0 + (chunk & 7) * 8, lA + chunk * 8);
    }
#pragma unroll
    for (int i = 0; i < CB; ++i) {
      int chunk = t + i * 256;
      async_cp16(B + (size_t)(chunk >> 3) * ldb + k0 + (chunk & 7) * 8, lB + chunk * 8);
    }
    __syncthreads();
#pragma unroll
    for (int ks = 0; ks < 2; ++ks) {
      bf16x8 af[FM], bfr[FN];
#pragma unroll
      for (int im = 0; im < FM; ++im)
        af[im] = *(const bf16x8*)(lA + (wm * FM * 16 + im * 16 + l16) * 64 + ks * 32 + quad * 8);
#pragma unroll
      for (int in = 0; in < FN; ++in)
        bfr[in] = *(const bf16x8*)(lB + (wn * FN * 16 + in * 16 + l16) * 64 + ks * 32 + quad * 8);
#pragma unroll
      for (int im = 0; im < FM; ++im)
#pragma unroll
        for (int in = 0; in < FN; ++in)
          acc[im][in] = __builtin_amdgcn_mfma_f32_16x16x32_bf16(af[im], bfr[in], acc[im][in], 0, 0, 0);
    }
    __syncthreads();
  }
}

// --- 1. means + bf16 cast. grid 4096 = [feat(2)][b*512+c(2048)], 256 thr ---
__global__ __launch_bounds__(256) void k_means_convert(
    const float* __restrict__ xc, const float* __restrict__ xs,
    u16* __restrict__ xcb, u16* __restrict__ xsb, float* __restrict__ mu) {
  int bx = blockIdx.x;
  int feat = bx >> 11;
  int row = bx & 2047;
  const float* src = (feat ? xs : xc) + (size_t)row * 16384;
  u16* dst = (feat ? xsb : xcb) + (size_t)row * 16384;
  int t = threadIdx.x;
  float s = 0.f;
#pragma unroll
  for (int i = 0; i < 16; ++i) {
    int idx = (t + i * 256) * 4;
    float4 v = *(const float4*)(src + idx);
    s += (v.x + v.y) + (v.z + v.w);
    ushort4 o;
    o.x = f2bf(v.x); o.y = f2bf(v.y); o.z = f2bf(v.z); o.w = f2bf(v.w);
    *(ushort4*)(dst + idx) = o;
  }
  __shared__ float red[256];
  red[t] = s;
  __syncthreads();
  for (int off = 128; off > 0; off >>= 1) {
    if (t < off) red[t] += red[t + off];
    __syncthreads();
  }
  if (t == 0) mu[bx] = red[0] * (1.f / 16384.f);
}

// --- 2. cov via split-K gram + folded mean/eps epilogue. grid (16,8,8) ---
__global__ __launch_bounds__(256) void k_gram(
    const u16* __restrict__ xcb, const u16* __restrict__ xsb,
    const float* __restrict__ mu, float* __restrict__ cov) {
  __shared__ u16 lA[128 * 64], lB[128 * 64];
  const int tile = blockIdx.x, split = blockIdx.y, mat = blockIdx.z;
  const int tm = tile & 3, tn = tile >> 2;
  const u16* X = (mat >= 4 ? xsb : xcb) + (size_t)(mat & 3) * 512 * 16384;
  const u16* A = X + (size_t)tm * 128 * 16384 + split * 2048;
  const u16* B = X + (size_t)tn * 128 * 16384 + split * 2048;
  f32x4 acc[4][4];
  gemm_nt<128, 128, 4, 4>(A, 16384, B, 16384, 2048, acc, lA, lB);
  const int lane = threadIdx.x & 63, wid = threadIdx.x >> 6;
  const int wm = wid & 1, wn = wid >> 1, l16 = lane & 15, quad = lane >> 4;
  const float* muf = mu + (mat >> 2) * 2048 + (mat & 3) * 512;
  float* C = cov + (size_t)mat * 262144;
  const float scale = 1.f / 16383.f;
  const bool base = (split == 0);
#pragma unroll
  for (int im = 0; im < 4; ++im)
#pragma unroll
    for (int in = 0; in < 4; ++in)
#pragma unroll
      for (int i = 0; i < 4; ++i) {
        int gm = tm * 128 + wm * 64 + im * 16 + quad * 4 + i;
        int gn = tn * 128 + wn * 64 + in * 16 + l16;
        float v = acc[im][in][i] * scale;
        if (base) v += (gm == gn ? 1e-5f : 0.f) - (16384.f / 16383.f) * muf[gm] * muf[gn];
        atomicAdd(C + gm * 512 + gn, v);
      }
}

// --- 3. Gershgorin bound: lam[mat] = max_i sum_j |A_ij| >= lambda_max ---
__global__ __launch_bounds__(256) void k_bound(const float* __restrict__ cov,
                                               float* __restrict__ lam) {
  const int mat = blockIdx.x, t = threadIdx.x;
  const float* A = cov + (size_t)mat * 262144;
  float mx = 0.f;
  for (int rr = 0; rr < 2; ++rr) {
    const float4* row = (const float4*)(A + (size_t)(t + rr * 256) * 512);
    float s = 0.f;
#pragma unroll 8
    for (int j = 0; j < 128; ++j) {
      float4 v = row[j];
      s += fabsf(v.x) + fabsf(v.y) + fabsf(v.z) + fabsf(v.w);
    }
    mx = fmaxf(mx, s);
  }
  __shared__ float red[256];
  red[t] = mx;
  __syncthreads();
  for (int off = 128; off > 0; off >>= 1) {
    if (t < off) red[t] = fmaxf(red[t], red[t + off]);
    __syncthreads();
  }
  if (t == 0) lam[mat] = red[0];
}

// --- 4. NS init: Y0 = A/lam (fp32 + bf16), Z0 = I; bias = mu_s. grid 8200 ---
__global__ __launch_bounds__(256) void k_nsinit(
    const float* __restrict__ cov, const float* __restrict__ lam,
    const float* __restrict__ mu, float* __restrict__ Yfp, float* __restrict__ Zfp,
    u16* __restrict__ Ybf, u16* __restrict__ Zbf, float* __restrict__ bias) {
  int bx = blockIdx.x;
  if (bx >= 8192) {
    int i = (bx - 8192) * 256 + threadIdx.x;  // 0..2047
    bias[i] = mu[2048 + i];                   // style means
    return;
  }
  int mat = bx >> 10;
  int idx = (bx & 1023) * 256 + threadIdx.x;
  int i = idx >> 9, j = idx & 511;
  size_t g = (size_t)mat * 262144 + idx;
  float a = cov[g] / lam[mat];
  float z = (i == j) ? 1.f : 0.f;
  Yfp[g] = a; Zfp[g] = z;
  Ybf[g] = f2bf(a); Zbf[g] = f2bf(z);
}

// --- 5a. NS phase1: D = (I - Z*Y)/2 (Y symmetric -> NT). grid (64,1,8) ---
__global__ __launch_bounds__(256) void k_ns1(const u16* __restrict__ Zbf,
                                             const u16* __restrict__ Ybf,
                                             u16* __restrict__ Dbf) {
  __shared__ u16 lA[64 * 64], lB[64 * 64];
  const int tile = blockIdx.x, mat = blockIdx.z;
  const int tm = tile & 7, tn = tile >> 3;
  const u16* A = Zbf + (size_t)mat * 262144 + tm * 64 * 512;
  const u16* B = Ybf + (size_t)mat * 262144 + tn * 64 * 512;
  f32x4 acc[2][2];
  gemm_nt<64, 64, 2, 2>(A, 512, B, 512, 512, acc, lA, lB);
  const int lane = threadIdx.x & 63, wid = threadIdx.x >> 6;
  const int wm = wid & 1, wn = wid >> 1, l16 = lane & 15, quad = lane >> 4;
  u16* D = Dbf + (size_t)mat * 262144;
#pragma unroll
  for (int im = 0; im < 2; ++im)
#pragma unroll
    for (int in = 0; in < 2; ++in)
#pragma unroll
      for (int i = 0; i < 4; ++i) {
        int gm = tm * 64 + wm * 32 + im * 16 + quad * 4 + i;
        int gn = tn * 64 + wn * 32 + in * 16 + l16;
        float d = 0.5f * ((gm == gn ? 1.f : 0.f) - acc[im][in][i]);
        D[gm * 512 + gn] = f2bf(d);
      }
}

// --- 5b. NS phase2: Y += Y*D ; Z += D*Z (D,Z symmetric -> NT). grid (64,1,16) ---
__global__ __launch_bounds__(256) void k_ns2(
    const u16* __restrict__ Ybf, const u16* __restrict__ Zbf, const u16* __restrict__ Dbf,
    float* __restrict__ Yfp, float* __restrict__ Zfp,
    u16* __restrict__ Ybn, u16* __restrict__ Zbn) {
  __shared__ u16 lA[64 * 64], lB[64 * 64];
  const int tile = blockIdx.x, z = blockIdx.z;
  const int kind = z >> 3, mat = z & 7;
  const int tm = tile & 7, tn = tile >> 3;
  size_t mo = (size_t)mat * 262144;
  const u16* A; const u16* B; float* M; u16* O;
  if (kind == 0) { A = Ybf + mo; B = Dbf + mo; M = Yfp + mo; O = Ybn + mo; }
  else           { A = Dbf + mo; B = Zbf + mo; M = Zfp + mo; O = Zbn + mo; }
  f32x4 acc[2][2];
  gemm_nt<64, 64, 2, 2>(A + tm * 64 * 512, 512, B + tn * 64 * 512, 512, 512, acc, lA, lB);
  const int lane = threadIdx.x & 63, wid = threadIdx.x >> 6;
  const int wm = wid & 1, wn = wid >> 1, l16 = lane & 15, quad = lane >> 4;
#pragma unroll
  for (int im = 0; im < 2; ++im)
#pragma unroll
    for (int in = 0; in < 2; ++in)
#pragma unroll
      for (int i = 0; i < 4; ++i) {
        int gm = tm * 64 + wm * 32 + im * 16 + quad * 4 + i;
        int gn = tn * 64 + wn * 32 + in * 16 + l16;
        float v = acc[im][in][i] + M[gm * 512 + gn];   // own tile: in-place safe
        M[gm * 512 + gn] = v;
        O[gm * 512 + gn] = f2bf(v);
      }
}

// --- 6. transpose content bf16 [c][n] -> [n][c] for NT apply. grid (256,8,4) ---
__global__ __launch_bounds__(256) void k_transpose(const u16* __restrict__ Xcb,
                                                   u16* __restrict__ Xct) {
  __shared__ u16 tb[64][72];
  const int t = threadIdx.x;
  const size_t base = (size_t)blockIdx.z * 512 * 16384;
  const int n0 = blockIdx.x * 64, c0 = blockIdx.y * 64;
#pragma unroll
  for (int i = 0; i < 2; ++i) {
    int chunk = t + i * 256;
    int r = chunk >> 3, cc = chunk & 7;
    uint4 v = *(const uint4*)(Xcb + base + (size_t)(c0 + r) * 16384 + n0 + cc * 8);
    const u16* e = (const u16*)&v;
#pragma unroll
    for (int j = 0; j < 8; ++j) tb[cc * 8 + j][r] = e[j];
  }
  __syncthreads();
  const size_t obase = (size_t)blockIdx.z * 16384 * 512;
#pragma unroll
  for (int i = 0; i < 2; ++i) {
    int chunk = t + i * 256;
    int r = chunk >> 3, cc = chunk & 7;
    u16 tmp[8];
#pragma unroll
    for (int j = 0; j < 8; ++j) tmp[j] = tb[r][cc * 8 + j];
    *(uint4*)(Xct + obase + (size_t)(n0 + r) * 512 + c0 + cc * 8) = *(const uint4*)tmp;
  }
}

// --- 7. T = sqrt(lam_s/lam_c) * Y_s * Z_c ; bias -= T*mu_c. grid (16,1,4) ---
__global__ __launch_bounds__(256) void k_compose(
    const u16* __restrict__ Ybf, const u16* __restrict__ Zbf,
    const float* __restrict__ lam, const float* __restrict__ mu,
    float* __restrict__ bias, u16* __restrict__ Tbf) {
  __shared__ u16 lA[128 * 64], lB[128 * 64];
  const int tile = blockIdx.x, b = blockIdx.z;
  const int tm = tile & 3, tn = tile >> 2;
  const u16* A = Ybf + (size_t)(4 + b) * 262144 + tm * 128 * 512;  // style Y
  const u16* B = Zbf + (size_t)b * 262144 + tn * 128 * 512;        // content Z (sym)
  f32x4 acc[4][4];
  gemm_nt<128, 128, 4, 4>(A, 512, B, 512, 512, acc, lA, lB);
  const int lane = threadIdx.x & 63, wid = threadIdx.x >> 6;
  const int wm = wid & 1, wn = wid >> 1, l16 = lane & 15, quad = lane >> 4;
  const float scale = sqrtf(lam[4 + b] / lam[b]);
  const float* muc = mu + b * 512;
  u16* T = Tbf + (size_t)b * 262144;
#pragma unroll
  for (int im = 0; im < 4; ++im)
#pragma unroll
    for (int i = 0; i < 4; ++i) {
      int gm = tm * 128 + wm * 64 + im * 16 + quad * 4 + i;
      float s = 0.f;
#pragma unroll
      for (int in = 0; in < 4; ++in) {
        int gn = tn * 128 + wn * 64 + in * 16 + l16;
        float tv = acc[im][in][i] * scale;
        T[gm * 512 + gn] = f2bf(tv);
        s += tv * muc[gn];
      }
      atomicAdd(&bias[b * 512 + gm], -s);
    }
}

// --- 8. out = T * xc + bias. grid (512,1,4) ---
__global__ __launch_bounds__(256) void k_apply(
    const u16* __restrict__ Tbf, const u16* __restrict__ Xct,
    const float* __restrict__ bias, float* __restrict__ out) {
  __shared__ u16 lA[128 * 64], lB[128 * 64];
  const int bx = blockIdx.x, b = blockIdx.z;
  const int tm = bx & 3, tn = bx >> 2;
  const u16* A = Tbf + (size_t)b * 262144 + tm * 128 * 512;
  const u16* B = Xct + (size_t)b * 16384 * 512 + (size_t)tn * 128 * 512;
  f32x4 acc[4][4];
  gemm_nt<128, 128, 4, 4>(A, 512, B, 512, 512, acc, lA, lB);
  const int lane = threadIdx.x & 63, wid = threadIdx.x >> 6;
  const int wm = wid & 1, wn = wid >> 1, l16 = lane & 15, quad = lane >> 4;
#pragma unroll
  for (int im = 0; im < 4; ++im)
#pragma unroll
    for (int in = 0; in < 4; ++in)
#pragma unroll
      for (int i = 0; i < 4; ++i) {
        int gm = tm * 128 + wm * 64 + im * 16 + quad * 4 + i;
        int gn = tn * 128 + wn * 64 + in * 16 + l16;
        out[((size_t)b * 512 + gm) * 16384 + gn] = acc[im][in][i] + bias[b * 512 + gm];
      }
}

extern "C" void kernel_launch(void* const* d_in, const int* in_sizes, int n_in,
                              void* d_out, int out_size, void* d_ws, size_t ws_size,
                              hipStream_t stream) {
  (void)in_sizes; (void)n_in; (void)out_size; (void)ws_size;
  const float* xc = (const float*)d_in[0];
  const float* xs = (const float*)d_in[1];
  float* out = (float*)d_out;
  char* w = (char*)d_ws;

  u16*   XA   = (u16*)(w);                      // content bf16 [b][c][n]   67.1 MB
  u16*   XB   = (u16*)(w + 67108864);           // style bf16 -> later Xct  67.1 MB
  float* cov  = (float*)(w + 134217728);        // 8 x 512^2 fp32
  float* Yfp  = (float*)(w + 142606336);
  float* Zfp  = (float*)(w + 150994944);
  u16*   Ybf0 = (u16*)(w + 159383552);
  u16*   Ybf1 = (u16*)(w + 163577856);
  u16*   Zbf0 = (u16*)(w + 167772160);
  u16*   Zbf1 = (u16*)(w + 171966464);
  u16*   Dbf  = (u16*)(w + 176160768);
  u16*   Tbf  = (u16*)(w + 180355072);
  float* mu   = (float*)(w + 182452224);        // [2][2048]
  float* lam  = (float*)(w + 182468608);        // [8]
  float* bias = (float*)(w + 182468864);        // [4][512]

  hipMemsetAsync(cov, 0, 8388608, stream);
  k_means_convert<<<4096, 256, 0, stream>>>(xc, xs, XA, XB, mu);
  k_gram<<<dim3(16, 8, 8), 256, 0, stream>>>(XA, XB, mu, cov);
  k_bound<<<8, 256, 0, stream>>>(cov, lam);
  k_nsinit<<<8200, 256, 0, stream>>>(cov, lam, mu, Yfp, Zfp, Ybf0, Zbf0, bias);
  k_transpose<<<dim3(256, 8, 4), 256, 0, stream>>>(XA, XB);  // XB now = Xct

  u16 *Yc = Ybf0, *Yn = Ybf1, *Zc = Zbf0, *Zn = Zbf1;
  for (int it = 0; it < 8; ++it) {
    k_ns1<<<dim3(64, 1, 8), 256, 0, stream>>>(Zc, Yc, Dbf);
    k_ns2<<<dim3(64, 1, 16), 256, 0, stream>>>(Yc, Zc, Dbf, Yfp, Zfp, Yn, Zn);
    u16* t1 = Yc; Yc = Yn; Yn = t1;
    u16* t2 = Zc; Zc = Zn; Zn = t2;
  }

  k_compose<<<dim3(16, 1, 4), 256, 0, stream>>>(Yc, Zc, lam, mu, bias, Tbf);
  k_apply<<<dim3(512, 1, 4), 256, 0, stream>>>(Tbf, XB, bias, out);
}

// Round 2
// 871.685 us; speedup vs baseline: 1.0596x; 1.0596x over previous
//
#include <hip/hip_runtime.h>

// WCT: out = S^(1/2) C^(-1/2) (xc - mu_c) + mu_s  per batch.
// B=4, C=512, H=W=128, N=16384. bf16 MFMA GEMMs, coupled Newton-Schulz (7 it).
// R2: 256-tile gram (logical traffic 1.07GB->384MB), XOR-swizzled LDS (16-way
// bank conflict -> 2-way), 7 NS iters.

typedef unsigned short u16;
typedef __attribute__((ext_vector_type(8))) short bf16x8;
typedef __attribute__((ext_vector_type(4))) float f32x4;

__device__ __forceinline__ u16 f2bf(float f) {  // RNE fp32->bf16
  unsigned u = __float_as_uint(f);
  u += 0x7fffu + ((u >> 16) & 1u);
  return (u16)(u >> 16);
}

__device__ __forceinline__ void async_cp16(const u16* g, u16* l) {
  __builtin_amdgcn_global_load_lds((__attribute__((address_space(1))) void*)g,
                                   (__attribute__((address_space(3))) void*)l,
                                   16, 0, 0);
}

// NT GEMM core: C[M,N] = A[M,K] * B[N,K]^T, bf16, 16x16x32 MFMA, BK=64.
// LDS layout XOR-swizzled: global 16B-chunk j' of row r is staged at slot
// j'^(r&7) by permuting the GLOBAL source address (LDS dest of
// global_load_lds is fixed to lane*16). Fragment reads then land 2-way
// bank-aliased (free) instead of 16-way.
// NT threads as WM x WN waves; wave tile (FM*16) x (FN*16).
template<int BM, int BN, int FM, int FN, int NT, int WM, int WN>
__device__ __forceinline__ void gemm_core(const u16* __restrict__ A, int lda,
                                          const u16* __restrict__ B, int ldb,
                                          int K, f32x4 (&acc)[FM][FN],
                                          u16* lA, u16* lB, bool stageB) {
  const int t = threadIdx.x;
  const int lane = t & 63;
  const int wid = t >> 6;
  const int wm = wid % WM, wn = wid / WM;
  const int l16 = lane & 15, quad = lane >> 4;
  const int sw = l16 & 7;  // fragment-read swizzle key (= row&7)
  f32x4 zero = {0.f, 0.f, 0.f, 0.f};
#pragma unroll
  for (int im = 0; im < FM; ++im)
#pragma unroll
    for (int in = 0; in < FN; ++in) acc[im][in] = zero;

  constexpr int CA = (BM * 8) / NT;  // 16B chunks per thread, A tile
  constexpr int CB = (BN * 8) / NT;

  for (int k0 = 0; k0 < K; k0 += 64) {
#pragma unroll
    for (int i = 0; i < CA; ++i) {
      int c = t + i * NT;  // LDS offset = c*16B (wave-uniform base + lane*16)
      int row = c >> 3;
      int src = (c & 7) ^ (row & 7);  // which global chunk lands in this slot
      async_cp16(A + (size_t)row * lda + k0 + src * 8, lA + c * 8);
    }
    if (stageB) {
#pragma unroll
      for (int i = 0; i < CB; ++i) {
        int c = t + i * NT;
        int row = c >> 3;
        int src = (c & 7) ^ (row & 7);
        async_cp16(B + (size_t)row * ldb + k0 + src * 8, lB + c * 8);
      }
    }
    __syncthreads();
#pragma unroll
    for (int ks = 0; ks < 2; ++ks) {
      bf16x8 af[FM], bfr[FN];
#pragma unroll
      for (int im = 0; im < FM; ++im)
        af[im] = *(const bf16x8*)(lA + ((wm * FM + im) * 16 + l16) * 64 +
                                  (((ks * 4 + quad) ^ sw) * 8));
#pragma unroll
      for (int in = 0; in < FN; ++in)
        bfr[in] = *(const bf16x8*)(lB + ((wn * FN + in) * 16 + l16) * 64 +
                                   (((ks * 4 + quad) ^ sw) * 8));
#pragma unroll
      for (int im = 0; im < FM; ++im)
#pragma unroll
        for (int in = 0; in < FN; ++in)
          acc[im][in] = __builtin_amdgcn_mfma_f32_16x16x32_bf16(af[im], bfr[in], acc[im][in], 0, 0, 0);
    }
    __syncthreads();
  }
}

// --- 1. means + bf16 cast. grid 4096 = [feat(2)][b*512+c(2048)], 256 thr ---
__global__ __launch_bounds__(256) void k_means_convert(
    const float* __restrict__ xc, const float* __restrict__ xs,
    u16* __restrict__ xcb, u16* __restrict__ xsb, float* __restrict__ mu) {
  int bx = blockIdx.x;
  int feat = bx >> 11;
  int row = bx & 2047;
  const float* src = (feat ? xs : xc) + (size_t)row * 16384;
  u16* dst = (feat ? xsb : xcb) + (size_t)row * 16384;
  int t = threadIdx.x;
  float s = 0.f;
#pragma unroll
  for (int i = 0; i < 16; ++i) {
    int idx = (t + i * 256) * 4;
    float4 v = *(const float4*)(src + idx);
    s += (v.x + v.y) + (v.z + v.w);
    ushort4 o;
    o.x = f2bf(v.x); o.y = f2bf(v.y); o.z = f2bf(v.z); o.w = f2bf(v.w);
    *(ushort4*)(dst + idx) = o;
  }
  __shared__ float red[256];
  red[t] = s;
  __syncthreads();
  for (int off = 128; off > 0; off >>= 1) {
    if (t < off) red[t] += red[t + off];
    __syncthreads();
  }
  if (t == 0) mu[bx] = red[0] * (1.f / 16384.f);
}

// --- 2. cov: 256x256 tiles, diag A/B-share, split-K=8. grid (4,8,8) ---
__global__ __launch_bounds__(512, 2) void k_gram(
    const u16* __restrict__ xcb, const u16* __restrict__ xsb,
    const float* __restrict__ mu, float* __restrict__ cov) {
  __shared__ u16 lds[2 * 256 * 64];
  const int tile = blockIdx.x, split = blockIdx.y, mat = blockIdx.z;
  const int tm = tile & 1, tn = tile >> 1;
  const u16* X = (mat >= 4 ? xsb : xcb) + (size_t)(mat & 3) * 512 * 16384;
  const u16* A = X + (size_t)tm * 256 * 16384 + split * 2048;
  const u16* B = X + (size_t)tn * 256 * 16384 + split * 2048;
  u16* lA = lds;
  u16* lB = (tm == tn) ? lds : lds + 256 * 64;
  f32x4 acc[8][4];
  gemm_core<256, 256, 8, 4, 512, 2, 4>(A, 16384, B, 16384, 2048, acc, lA, lB, tm != tn);
  const int lane = threadIdx.x & 63, wid = threadIdx.x >> 6;
  const int wm = wid % 2, wn = wid / 2, l16 = lane & 15, quad = lane >> 4;
  const float* muf = mu + (mat >> 2) * 2048 + (mat & 3) * 512;
  float* C = cov + (size_t)mat * 262144;
  const float scale = 1.f / 16383.f;
  const bool base = (split == 0);
#pragma unroll
  for (int im = 0; im < 8; ++im)
#pragma unroll
    for (int in = 0; in < 4; ++in)
#pragma unroll
      for (int i = 0; i < 4; ++i) {
        int gm = tm * 256 + wm * 128 + im * 16 + quad * 4 + i;
        int gn = tn * 256 + wn * 64 + in * 16 + l16;
        float v = acc[im][in][i] * scale;
        if (base) v += (gm == gn ? 1e-5f : 0.f) - (16384.f / 16383.f) * muf[gm] * muf[gn];
        atomicAdd(C + gm * 512 + gn, v);
      }
}

// --- 3. Gershgorin bound: lam[mat] = max_i sum_j |A_ij| >= lambda_max ---
__global__ __launch_bounds__(256) void k_bound(const float* __restrict__ cov,
                                               float* __restrict__ lam) {
  const int mat = blockIdx.x, t = threadIdx.x;
  const float* A = cov + (size_t)mat * 262144;
  float mx = 0.f;
  for (int rr = 0; rr < 2; ++rr) {
    const float4* row = (const float4*)(A + (size_t)(t + rr * 256) * 512);
    float s = 0.f;
#pragma unroll 8
    for (int j = 0; j < 128; ++j) {
      float4 v = row[j];
      s += fabsf(v.x) + fabsf(v.y) + fabsf(v.z) + fabsf(v.w);
    }
    mx = fmaxf(mx, s);
  }
  __shared__ float red[256];
  red[t] = mx;
  __syncthreads();
  for (int off = 128; off > 0; off >>= 1) {
    if (t < off) red[t] = fmaxf(red[t], red[t + off]);
    __syncthreads();
  }
  if (t == 0) lam[mat] = red[0];
}

// --- 4. NS init: Y0 = A/lam (fp32 + bf16), Z0 = I; bias = mu_s. grid 8200 ---
__global__ __launch_bounds__(256) void k_nsinit(
    const float* __restrict__ cov, const float* __restrict__ lam,
    const float* __restrict__ mu, float* __restrict__ Yfp, float* __restrict__ Zfp,
    u16* __restrict__ Ybf, u16* __restrict__ Zbf, float* __restrict__ bias) {
  int bx = blockIdx.x;
  if (bx >= 8192) {
    int i = (bx - 8192) * 256 + threadIdx.x;  // 0..2047
    bias[i] = mu[2048 + i];                   // style means
    return;
  }
  int mat = bx >> 10;
  int idx = (bx & 1023) * 256 + threadIdx.x;
  int i = idx >> 9, j = idx & 511;
  size_t g = (size_t)mat * 262144 + idx;
  float a = cov[g] / lam[mat];
  float z = (i == j) ? 1.f : 0.f;
  Yfp[g] = a; Zfp[g] = z;
  Ybf[g] = f2bf(a); Zbf[g] = f2bf(z);
}

// --- 5a. NS phase1: D = (I - Z*Y)/2 (Y symmetric -> NT). grid (64,1,8) ---
__global__ __launch_bounds__(256) void k_ns1(const u16* __restrict__ Zbf,
                                             const u16* __restrict__ Ybf,
                                             u16* __restrict__ Dbf) {
  __shared__ u16 lds[2 * 64 * 64];
  const int tile = blockIdx.x, mat = blockIdx.z;
  const int tm = tile & 7, tn = tile >> 3;
  const u16* A = Zbf + (size_t)mat * 262144 + tm * 64 * 512;
  const u16* B = Ybf + (size_t)mat * 262144 + tn * 64 * 512;
  f32x4 acc[2][2];
  gemm_core<64, 64, 2, 2, 256, 2, 2>(A, 512, B, 512, 512, acc, lds, lds + 4096, true);
  const int lane = threadIdx.x & 63, wid = threadIdx.x >> 6;
  const int wm = wid % 2, wn = wid / 2, l16 = lane & 15, quad = lane >> 4;
  u16* D = Dbf + (size_t)mat * 262144;
#pragma unroll
  for (int im = 0; im < 2; ++im)
#pragma unroll
    for (int in = 0; in < 2; ++in)
#pragma unroll
      for (int i = 0; i < 4; ++i) {
        int gm = tm * 64 + wm * 32 + im * 16 + quad * 4 + i;
        int gn = tn * 64 + wn * 32 + in * 16 + l16;
        float d = 0.5f * ((gm == gn ? 1.f : 0.f) - acc[im][in][i]);
        D[gm * 512 + gn] = f2bf(d);
      }
}

// --- 5b. NS phase2: Y += Y*D ; Z += D*Z (D,Z symmetric -> NT). grid (64,1,16) ---
__global__ __launch_bounds__(256) void k_ns2(
    const u16* __restrict__ Ybf, const u16* __restrict__ Zbf, const u16* __restrict__ Dbf,
    float* __restrict__ Yfp, float* __restrict__ Zfp,
    u16* __restrict__ Ybn, u16* __restrict__ Zbn) {
  __shared__ u16 lds[2 * 64 * 64];
  const int tile = blockIdx.x, z = blockIdx.z;
  const int kind = z >> 3, mat = z & 7;
  const int tm = tile & 7, tn = tile >> 3;
  size_t mo = (size_t)mat * 262144;
  const u16* A; const u16* B; float* M; u16* O;
  if (kind == 0) { A = Ybf + mo; B = Dbf + mo; M = Yfp + mo; O = Ybn + mo; }
  else           { A = Dbf + mo; B = Zbf + mo; M = Zfp + mo; O = Zbn + mo; }
  f32x4 acc[2][2];
  gemm_core<64, 64, 2, 2, 256, 2, 2>(A + tm * 64 * 512, 512, B + tn * 64 * 512, 512, 512,
                                     acc, lds, lds + 4096, true);
  const int lane = threadIdx.x & 63, wid = threadIdx.x >> 6;
  const int wm = wid % 2, wn = wid / 2, l16 = lane & 15, quad = lane >> 4;
#pragma unroll
  for (int im = 0; im < 2; ++im)
#pragma unroll
    for (int in = 0; in < 2; ++in)
#pragma unroll
      for (int i = 0; i < 4; ++i) {
        int gm = tm * 64 + wm * 32 + im * 16 + quad * 4 + i;
        int gn = tn * 64 + wn * 32 + in * 16 + l16;
        float v = acc[im][in][i] + M[gm * 512 + gn];   // own tile: in-place safe
        M[gm * 512 + gn] = v;
        O[gm * 512 + gn] = f2bf(v);
      }
}

// --- 6. transpose content bf16 [c][n] -> [n][c] for NT apply. grid (256,8,4) ---
__global__ __launch_bounds__(256) void k_transpose(const u16* __restrict__ Xcb,
                                                   u16* __restrict__ Xct) {
  __shared__ u16 tb[64][72];
  const int t = threadIdx.x;
  const size_t base = (size_t)blockIdx.z * 512 * 16384;
  const int n0 = blockIdx.x * 64, c0 = blockIdx.y * 64;
#pragma unroll
  for (int i = 0; i < 2; ++i) {
    int chunk = t + i * 256;
    int r = chunk >> 3, cc = chunk & 7;
    uint4 v = *(const uint4*)(Xcb + base + (size_t)(c0 + r) * 16384 + n0 + cc * 8);
    const u16* e = (const u16*)&v;
#pragma unroll
    for (int j = 0; j < 8; ++j) tb[cc * 8 + j][r] = e[j];
  }
  __syncthreads();
  const size_t obase = (size_t)blockIdx.z * 16384 * 512;
#pragma unroll
  for (int i = 0; i < 2; ++i) {
    int chunk = t + i * 256;
    int r = chunk >> 3, cc = chunk & 7;
    u16 tmp[8];
#pragma unroll
    for (int j = 0; j < 8; ++j) tmp[j] = tb[r][cc * 8 + j];
    *(uint4*)(Xct + obase + (size_t)(n0 + r) * 512 + c0 + cc * 8) = *(const uint4*)tmp;
  }
}

// --- 7. T = sqrt(lam_s/lam_c) * Y_s * Z_c ; bias -= T*mu_c. grid (16,1,4) ---
__global__ __launch_bounds__(256) void k_compose(
    const u16* __restrict__ Ybf, const u16* __restrict__ Zbf,
    const float* __restrict__ lam, const float* __restrict__ mu,
    float* __restrict__ bias, u16* __restrict__ Tbf) {
  __shared__ u16 lds[2 * 128 * 64];
  const int tile = blockIdx.x, b = blockIdx.z;
  const int tm = tile & 3, tn = tile >> 2;
  const u16* A = Ybf + (size_t)(4 + b) * 262144 + tm * 128 * 512;  // style Y
  const u16* B = Zbf + (size_t)b * 262144 + tn * 128 * 512;        // content Z (sym)
  f32x4 acc[4][4];
  gemm_core<128, 128, 4, 4, 256, 2, 2>(A, 512, B, 512, 512, acc, lds, lds + 8192, true);
  const int lane = threadIdx.x & 63, wid = threadIdx.x >> 6;
  const int wm = wid % 2, wn = wid / 2, l16 = lane & 15, quad = lane >> 4;
  const float scale = sqrtf(lam[4 + b] / lam[b]);
  const float* muc = mu + b * 512;
  u16* T = Tbf + (size_t)b * 262144;
#pragma unroll
  for (int im = 0; im < 4; ++im)
#pragma unroll
    for (int i = 0; i < 4; ++i) {
      int gm = tm * 128 + wm * 64 + im * 16 + quad * 4 + i;
      float s = 0.f;
#pragma unroll
      for (int in = 0; in < 4; ++in) {
        int gn = tn * 128 + wn * 64 + in * 16 + l16;
        float tv = acc[im][in][i] * scale;
        T[gm * 512 + gn] = f2bf(tv);
        s += tv * muc[gn];
      }
      atomicAdd(&bias[b * 512 + gm], -s);
    }
}

// --- 8. out = T * xc + bias. grid (512,1,4) ---
__global__ __launch_bounds__(256) void k_apply(
    const u16* __restrict__ Tbf, const u16* __restrict__ Xct,
    const float* __restrict__ bias, float* __restrict__ out) {
  __shared__ u16 lds[2 * 128 * 64];
  const int bx = blockIdx.x, b = blockIdx.z;
  const int tm = bx & 3, tn = bx >> 2;
  const u16* A = Tbf + (size_t)b * 262144 + tm * 128 * 512;
  const u16* B = Xct + (size_t)b * 16384 * 512 + (size_t)tn * 128 * 512;
  f32x4 acc[4][4];
  gemm_core<128, 128, 4, 4, 256, 2, 2>(A, 512, B, 512, 512, acc, lds, lds + 8192, true);
  const int lane = threadIdx.x & 63, wid = threadIdx.x >> 6;
  const int wm = wid % 2, wn = wid / 2, l16 = lane & 15, quad = lane >> 4;
#pragma unroll
  for (int im = 0; im < 4; ++im)
#pragma unroll
    for (int in = 0; in < 4; ++in)
#pragma unroll
      for (int i = 0; i < 4; ++i) {
        int gm = tm * 128 + wm * 64 + im * 16 + quad * 4 + i;
        int gn = tn * 128 + wn * 64 + in * 16 + l16;
        out[((size_t)b * 512 + gm) * 16384 + gn] = acc[im][in][i] + bias[b * 512 + gm];
      }
}

extern "C" void kernel_launch(void* const* d_in, const int* in_sizes, int n_in,
                              void* d_out, int out_size, void* d_ws, size_t ws_size,
                              hipStream_t stream) {
  (void)in_sizes; (void)n_in; (void)out_size; (void)ws_size;
  const float* xc = (const float*)d_in[0];
  const float* xs = (const float*)d_in[1];
  float* out = (float*)d_out;
  char* w = (char*)d_ws;

  u16*   XA   = (u16*)(w);                      // content bf16 [b][c][n]   67.1 MB
  u16*   XB   = (u16*)(w + 67108864);           // style bf16 -> later Xct  67.1 MB
  float* cov  = (float*)(w + 134217728);        // 8 x 512^2 fp32
  float* Yfp  = (float*)(w + 142606336);
  float* Zfp  = (float*)(w + 150994944);
  u16*   Ybf0 = (u16*)(w + 159383552);
  u16*   Ybf1 = (u16*)(w + 163577856);
  u16*   Zbf0 = (u16*)(w + 167772160);
  u16*   Zbf1 = (u16*)(w + 171966464);
  u16*   Dbf  = (u16*)(w + 176160768);
  u16*   Tbf  = (u16*)(w + 180355072);
  float* mu   = (float*)(w + 182452224);        // [2][2048]
  float* lam  = (float*)(w + 182468608);        // [8]
  float* bias = (float*)(w + 182468864);        // [4][512]

  hipMemsetAsync(cov, 0, 8388608, stream);
  k_means_convert<<<4096, 256, 0, stream>>>(xc, xs, XA, XB, mu);
  k_gram<<<dim3(4, 8, 8), 512, 0, stream>>>(XA, XB, mu, cov);
  k_bound<<<8, 256, 0, stream>>>(cov, lam);
  k_nsinit<<<8200, 256, 0, stream>>>(cov, lam, mu, Yfp, Zfp, Ybf0, Zbf0, bias);
  k_transpose<<<dim3(256, 8, 4), 256, 0, stream>>>(XA, XB);  // XB now = Xct

  u16 *Yc = Ybf0, *Yn = Ybf1, *Zc = Zbf0, *Zn = Zbf1;
  for (int it = 0; it < 7; ++it) {
    k_ns1<<<dim3(64, 1, 8), 256, 0, stream>>>(Zc, Yc, Dbf);
    k_ns2<<<dim3(64, 1, 16), 256, 0, stream>>>(Yc, Zc, Dbf, Yfp, Zfp, Yn, Zn);
    u16* t1 = Yc; Yc = Yn; Yn = t1;
    u16* t2 = Zc; Zc = Zn; Zn = t2;
  }

  k_compose<<<dim3(16, 1, 4), 256, 0, stream>>>(Yc, Zc, lam, mu, bias, Tbf);
  k_apply<<<dim3(512, 1, 4), 256, 0, stream>>>(Tbf, XB, bias, out);
}